// Round 7
// baseline (216.148 us; speedup 1.0000x reference)
//
#include <hip/hip_runtime.h>

// Problem constants from setup_inputs(): shape (64, 16, 64, 64), fp32, kern=2.
#define N_ 64
#define C_ 16
#define H_ 64
#define W_ 64

// pair_kernel tiling: 2 i-rows x 8 j-rows per tile, D split into 16 chunks.
// Chosen to keep VGPR <= 64: waves/SIMD halve at VGPR=64 (measured m69);
// R5/R6's 4x8 tile sat at VGPR=68 -> 4 waves/SIMD, 24% occupancy.
// tri sets (vaa, vbb): i-tile g (rows 2g,2g+1) needs j-tiles 0..(g>>2)
//   -> sum over g=0..31 of (g>>2)+1 = 144 tiles per set
// vab (full): 32 i-tiles x 8 j-tiles = 256. TILES = 144*2 + 256 = 544.
#define TRI_TILES 144
#define TILES 544
#define DCHUNKS 16
#define PAIR_BLOCKS (TILES * DCHUNKS)   // 8704

// NUMERICS: ws stores var' = var * 2ln2. Then exp(-0.5 d^2/v)/sqrt(v)
//   = exp2(-(d*rsq(v'))^2) * rsq(v') * sqrt(2ln2);
// sqrt(2ln2)=1.1774100 folds into the final scalar. 5 VALU + 2 transc / term.
#define TWO_LN2   1.3862943611198906f
#define SQRT_2LN2 1.1774100225154747f

// ws layout (floats): [0..Np) mu_a | [Np..2Np) var'_a | [2Np..3Np) mu_b | [3Np..4Np) var'_b

__global__ __launch_bounds__(256) void pool_kernel(
    const float* __restrict__ mu_a, const float* __restrict__ lv_a,
    const float* __restrict__ mu_b, const float* __restrict__ lv_b,
    const int* __restrict__ kern_p, float* __restrict__ ws,
    float* __restrict__ out) {
    if (blockIdx.x == 0 && threadIdx.x == 0) out[0] = 0.0f;  // pair runs after (stream order)

    const int k = kern_p[0];
    const float LOG2E = 1.44269504088896f;

    if (k == 2) {
        // Fast path: 4 contiguous pooled outputs per thread, all-shift indexing.
        const int Np = (N_ * C_ * H_ * W_) >> 2;  // 1048576
        const int Q  = Np >> 2;                   // 262144 quads per array
        const int total = 4 * Q;
        for (int g = blockIdx.x * blockDim.x + threadIdx.x; g < total;
             g += gridDim.x * blockDim.x) {
            const int a  = g >> 18;               // log2(Q) = 18
            const int r4 = g & (Q - 1);
            const int pw4 = (r4 & 7) << 2;        // Wp=32 -> 8 quads/row
            const int t   = r4 >> 3;
            const int ph  = t & 31;               // Hp=32
            const int nc  = t >> 5;
            const float* src = (a == 0) ? mu_a : (a == 1) ? lv_a : (a == 2) ? mu_b : lv_b;
            const bool is_var = (a & 1);
            const float* p0 = src + nc * (H_ * W_) + (ph * 2) * W_ + pw4 * 2;
            float4 r0a = *(const float4*)(p0);
            float4 r0b = *(const float4*)(p0 + 4);
            float4 r1a = *(const float4*)(p0 + W_);
            float4 r1b = *(const float4*)(p0 + W_ + 4);
            float o0, o1, o2, o3;
            if (is_var) {
#define E_(x) __builtin_amdgcn_exp2f((x) * LOG2E)
                o0 = E_(r0a.x) + E_(r0a.y) + E_(r1a.x) + E_(r1a.y);
                o1 = E_(r0a.z) + E_(r0a.w) + E_(r1a.z) + E_(r1a.w);
                o2 = E_(r0b.x) + E_(r0b.y) + E_(r1b.x) + E_(r1b.y);
                o3 = E_(r0b.z) + E_(r0b.w) + E_(r1b.z) + E_(r1b.w);
#undef E_
                const float s = (1.0f / 16.0f) * TWO_LN2;  // 1/k^4 * 2ln2
                o0 *= s; o1 *= s; o2 *= s; o3 *= s;
            } else {
                o0 = r0a.x + r0a.y + r1a.x + r1a.y;
                o1 = r0a.z + r0a.w + r1a.z + r1a.w;
                o2 = r0b.x + r0b.y + r1b.x + r1b.y;
                o3 = r0b.z + r0b.w + r1b.z + r1b.w;
                const float s = 0.25f;            // 1/k^2
                o0 *= s; o1 *= s; o2 *= s; o3 *= s;
            }
            *(float4*)(ws + (size_t)a * Np + (size_t)r4 * 4) = make_float4(o0, o1, o2, o3);
        }
    } else {
        // Generic fallback (any k dividing 64).
        const int Hp = H_ / k, Wp = W_ / k;
        const int Np = N_ * C_ * Hp * Wp;
        const float inv_k2 = 1.0f / (float)(k * k);
        const float inv_k4 = inv_k2 * inv_k2 * TWO_LN2;   // fold var pre-scale
        const int total = 4 * Np;
        for (int p = blockIdx.x * blockDim.x + threadIdx.x; p < total;
             p += gridDim.x * blockDim.x) {
            const int a  = p / Np;
            const int r  = p - a * Np;
            const int pw = r % Wp;
            const int t1 = r / Wp;
            const int ph = t1 % Hp;
            const int nc = t1 / Hp;
            const float* src = (a == 0) ? mu_a : (a == 1) ? lv_a : (a == 2) ? mu_b : lv_b;
            const bool is_var = (a & 1);
            const int base = nc * (H_ * W_) + (ph * k) * W_ + (pw * k);
            float s = 0.0f;
            for (int dy = 0; dy < k; ++dy) {
                const float* row = src + base + dy * W_;
                for (int dx = 0; dx < k; ++dx) {
                    float x = row[dx];
                    s += is_var ? __builtin_amdgcn_exp2f(x * LOG2E) : x;
                }
            }
            ws[(size_t)a * Np + r] = s * (is_var ? inv_k4 : inv_k2);
        }
    }
}

// block = (tile t, chunk c): 2 i-rows register-resident (1 float4 mu + var' each),
// 8 j-rows streamed. Per term: add, rsq, sub, mul, mul(neg), exp2, fma = 5V + 2T.
// NOTE: no min-waves clause — R3 showed __launch_bounds__(256,8) forces spills.
__global__ __launch_bounds__(256) void pair_kernel(const float* __restrict__ ws,
                                                   const int* __restrict__ kern_p,
                                                   float* __restrict__ out) {
    const int k = kern_p[0];
    const int D  = C_ * (H_ / k) * (W_ / k);
    const int Np = N_ * D;

    const float* mu_a = ws;
    const float* va   = ws + (size_t)Np;
    const float* mu_b = ws + (size_t)2 * Np;
    const float* vb   = ws + (size_t)3 * Np;

    // ---- decode block -> (set, i-tile, j-tile, chunk) ----
    const int c = blockIdx.x & (DCHUNKS - 1);
    const int t = blockIdx.x >> 4;           // DCHUNKS == 16
    int set, it, jt;
    if (t >= 2 * TRI_TILES) {
        set = 2;
        const int tt = t - 2 * TRI_TILES;
        it = tt >> 3;
        jt = tt & 7;
    } else {
        set = (t >= TRI_TILES) ? 1 : 0;
        const int tt = set ? (t - TRI_TILES) : t;
        // closed-form-ish decode: g = 4q+r, cum(g) = 2q(q+1) + r(q+1)
        int q = 0;
        while (q < 8 && 2 * (q + 1) * (q + 2) <= tt) ++q;
        const int rem = tt - 2 * q * (q + 1);
        const int r   = rem / (q + 1);       // 0..3 (row within quad-group)
        it = 4 * q + r;
        jt = rem - r * (q + 1);
    }
    const int i0 = it * 2, j0 = jt * 8;

    const float *mu1, *v1, *mu2, *v2;
    if (set == 0)      { mu1 = mu2 = mu_a; v1 = v2 = va; }
    else if (set == 1) { mu1 = mu2 = mu_b; v1 = v2 = vb; }
    else               { mu1 = mu_a; v1 = va; mu2 = mu_b; v2 = vb; }

#define TERM(acc, mx1, sx1, mx2, sx2)                                  \
    {                                                                  \
        float v  = (sx1) + (sx2);                                      \
        float rs = __builtin_amdgcn_rsqf(v);                           \
        float d  = (mx1) - (mx2);                                      \
        float t_ = d * rs;                                             \
        float e  = __builtin_amdgcn_exp2f(-(t_ * t_));                 \
        acc = fmaf(e, rs, acc);                                        \
    }

    float accs[2][8];
    #pragma unroll
    for (int ir = 0; ir < 2; ++ir)
        #pragma unroll
        for (int j8 = 0; j8 < 8; ++j8) accs[ir][j8] = 0.0f;

    if (D == 16384) {
        // Fast path: chunk = 1024 elems = 256 threads x 1 float4.
        const int base = (c << 10) + ((int)threadIdx.x << 2);
        float4 im[2], iv[2];
        #pragma unroll
        for (int ir = 0; ir < 2; ++ir) {
            im[ir] = *(const float4*)(mu1 + (size_t)(i0 + ir) * 16384 + base);
            iv[ir] = *(const float4*)(v1  + (size_t)(i0 + ir) * 16384 + base);
        }
        #pragma unroll
        for (int j8 = 0; j8 < 8; ++j8) {
            const float4 jm = *(const float4*)(mu2 + (size_t)(j0 + j8) * 16384 + base);
            const float4 jv = *(const float4*)(v2  + (size_t)(j0 + j8) * 16384 + base);
            #pragma unroll
            for (int ir = 0; ir < 2; ++ir) {
                TERM(accs[ir][j8], im[ir].x, iv[ir].x, jm.x, jv.x)
                TERM(accs[ir][j8], im[ir].y, iv[ir].y, jm.y, jv.y)
                TERM(accs[ir][j8], im[ir].z, iv[ir].z, jm.z, jv.z)
                TERM(accs[ir][j8], im[ir].w, iv[ir].w, jm.w, jv.w)
            }
        }
    } else {
        // Generic fallback: chunk c covers [c*D/16, (c+1)*D/16), scalar loads.
        const int cs = D / DCHUNKS;
        const int lo = c * cs, hi = lo + cs;
        for (int e = lo + (int)threadIdx.x; e < hi; e += 256) {
            #pragma unroll
            for (int j8 = 0; j8 < 8; ++j8) {
                const float mj = mu2[(size_t)(j0 + j8) * D + e];
                const float vj = v2 [(size_t)(j0 + j8) * D + e];
                #pragma unroll
                for (int ir = 0; ir < 2; ++ir) {
                    const float mi = mu1[(size_t)(i0 + ir) * D + e];
                    const float vi = v1 [(size_t)(i0 + ir) * D + e];
                    TERM(accs[ir][j8], mi, vi, mj, vj)
                }
            }
        }
    }
#undef TERM

    float tot = 0.0f;
    #pragma unroll
    for (int ir = 0; ir < 2; ++ir) {
        #pragma unroll
        for (int j8 = 0; j8 < 8; ++j8) {
            float w;
            if (set == 2) w = -2.0f;
            else {
                const int ii = i0 + ir, jj = j0 + j8;
                w = (jj > ii) ? 0.0f : (jj == ii) ? 1.0f : 2.0f;
            }
            tot = fmaf(w, accs[ir][j8], tot);
        }
    }
    tot *= SQRT_2LN2;   // fold the var'-prescale correction once

    for (int off = 32; off > 0; off >>= 1)
        tot += __shfl_down(tot, off, 64);
    __shared__ float wsum[4];
    const int lane = threadIdx.x & 63;
    const int wid  = threadIdx.x >> 6;
    if (lane == 0) wsum[wid] = tot;
    __syncthreads();
    if (threadIdx.x == 0) {
        atomicAdd(out, wsum[0] + wsum[1] + wsum[2] + wsum[3]);
    }
}

extern "C" void kernel_launch(void* const* d_in, const int* in_sizes, int n_in,
                              void* d_out, int out_size, void* d_ws, size_t ws_size,
                              hipStream_t stream) {
    const float* mu_a = (const float*)d_in[0];
    const float* lv_a = (const float*)d_in[1];
    const float* mu_b = (const float*)d_in[2];
    const float* lv_b = (const float*)d_in[3];
    const int*   kern = (const int*)d_in[4];
    float* out = (float*)d_out;
    float* ws  = (float*)d_ws;

    pool_kernel<<<4096, 256, 0, stream>>>(mu_a, lv_a, mu_b, lv_b, kern, ws, out);
    pair_kernel<<<PAIR_BLOCKS, 256, 0, stream>>>(ws, kern, out);
}

// Round 8
// 143.076 us; speedup vs baseline: 1.5107x; 1.5107x over previous
//
#include <hip/hip_runtime.h>

// Problem constants from setup_inputs(): shape (64, 16, 64, 64), fp32, kern=2.
#define N_ 64
#define C_ 16
#define H_ 64
#define W_ 64

// pair_kernel tiling (R5 structure — best measured): 4 i-rows x 8 j-rows per
// tile, D split into 16 chunks of 1024.
// tri sets (vaa, vbb): i-tile g (rows 4g..4g+3) needs j-tiles 0..(g>>1)
//   -> sum over g=0..15 of (g>>1)+1 = 72 tiles per set
// vab (full): 16 i-tiles x 8 j-tiles = 128 tiles. TILES = 72*2 + 128 = 272.
#define TRI_TILES 72
#define TILES 272
#define DCHUNKS 16
#define PAIR_BLOCKS (TILES * DCHUNKS)   // 4352

// NUMERICS: ws stores var' = var * 2ln2. Then exp(-0.5 d^2/v)/sqrt(v)
//   = exp2(-(d*rsq(v'))^2) * rsq(v') * sqrt(2ln2);
// sqrt(2ln2)=1.1774100 folds into the per-block partial. 5 VALU + 2 transc/term.
#define TWO_LN2   1.3862943611198906f
#define SQRT_2LN2 1.1774100225154747f

// ws layout (floats): [0..Np) mu_a | [Np..2Np) var'_a | [2Np..3Np) mu_b |
// [3Np..4Np) var'_b | [4Np..4Np+PAIR_BLOCKS) per-block partials.
// R7 post-mortem: single-address atomicAdd tail ~6ns x nblocks serialized
// (~26us at 4352 blocks) — replaced by partial stores + 1-block reduce.

__global__ __launch_bounds__(256) void pool_kernel(
    const float* __restrict__ mu_a, const float* __restrict__ lv_a,
    const float* __restrict__ mu_b, const float* __restrict__ lv_b,
    const int* __restrict__ kern_p, float* __restrict__ ws) {
    const int k = kern_p[0];
    const float LOG2E = 1.44269504088896f;

    if (k == 2) {
        // Fast path: 4 contiguous pooled outputs per thread, all-shift indexing.
        const int Np = (N_ * C_ * H_ * W_) >> 2;  // 1048576
        const int Q  = Np >> 2;                   // 262144 quads per array
        const int total = 4 * Q;
        for (int g = blockIdx.x * blockDim.x + threadIdx.x; g < total;
             g += gridDim.x * blockDim.x) {
            const int a  = g >> 18;               // log2(Q) = 18
            const int r4 = g & (Q - 1);
            const int pw4 = (r4 & 7) << 2;        // Wp=32 -> 8 quads/row
            const int t   = r4 >> 3;
            const int ph  = t & 31;               // Hp=32
            const int nc  = t >> 5;
            const float* src = (a == 0) ? mu_a : (a == 1) ? lv_a : (a == 2) ? mu_b : lv_b;
            const bool is_var = (a & 1);
            const float* p0 = src + nc * (H_ * W_) + (ph * 2) * W_ + pw4 * 2;
            float4 r0a = *(const float4*)(p0);
            float4 r0b = *(const float4*)(p0 + 4);
            float4 r1a = *(const float4*)(p0 + W_);
            float4 r1b = *(const float4*)(p0 + W_ + 4);
            float o0, o1, o2, o3;
            if (is_var) {
#define E_(x) __builtin_amdgcn_exp2f((x) * LOG2E)
                o0 = E_(r0a.x) + E_(r0a.y) + E_(r1a.x) + E_(r1a.y);
                o1 = E_(r0a.z) + E_(r0a.w) + E_(r1a.z) + E_(r1a.w);
                o2 = E_(r0b.x) + E_(r0b.y) + E_(r1b.x) + E_(r1b.y);
                o3 = E_(r0b.z) + E_(r0b.w) + E_(r1b.z) + E_(r1b.w);
#undef E_
                const float s = (1.0f / 16.0f) * TWO_LN2;  // 1/k^4 * 2ln2
                o0 *= s; o1 *= s; o2 *= s; o3 *= s;
            } else {
                o0 = r0a.x + r0a.y + r1a.x + r1a.y;
                o1 = r0a.z + r0a.w + r1a.z + r1a.w;
                o2 = r0b.x + r0b.y + r1b.x + r1b.y;
                o3 = r0b.z + r0b.w + r1b.z + r1b.w;
                const float s = 0.25f;            // 1/k^2
                o0 *= s; o1 *= s; o2 *= s; o3 *= s;
            }
            *(float4*)(ws + (size_t)a * Np + (size_t)r4 * 4) = make_float4(o0, o1, o2, o3);
        }
    } else {
        // Generic fallback (any k dividing 64).
        const int Hp = H_ / k, Wp = W_ / k;
        const int Np = N_ * C_ * Hp * Wp;
        const float inv_k2 = 1.0f / (float)(k * k);
        const float inv_k4 = inv_k2 * inv_k2 * TWO_LN2;   // fold var pre-scale
        const int total = 4 * Np;
        for (int p = blockIdx.x * blockDim.x + threadIdx.x; p < total;
             p += gridDim.x * blockDim.x) {
            const int a  = p / Np;
            const int r  = p - a * Np;
            const int pw = r % Wp;
            const int t1 = r / Wp;
            const int ph = t1 % Hp;
            const int nc = t1 / Hp;
            const float* src = (a == 0) ? mu_a : (a == 1) ? lv_a : (a == 2) ? mu_b : lv_b;
            const bool is_var = (a & 1);
            const int base = nc * (H_ * W_) + (ph * k) * W_ + (pw * k);
            float s = 0.0f;
            for (int dy = 0; dy < k; ++dy) {
                const float* row = src + base + dy * W_;
                for (int dx = 0; dx < k; ++dx) {
                    float x = row[dx];
                    s += is_var ? __builtin_amdgcn_exp2f(x * LOG2E) : x;
                }
            }
            ws[(size_t)a * Np + r] = s * (is_var ? inv_k4 : inv_k2);
        }
    }
}

// block = (tile t, chunk c): 4 i-rows register-resident (1 float4 mu + var' each),
// 8 j-rows streamed. Per term: add, rsq, sub, mul, mul(neg), exp2, fma = 5V + 2T.
// NOTE: no min-waves clause — R3 showed __launch_bounds__(256,8) forces spills.
__global__ __launch_bounds__(256) void pair_kernel(float* __restrict__ ws,
                                                   const int* __restrict__ kern_p) {
    const int k = kern_p[0];
    const int D  = C_ * (H_ / k) * (W_ / k);
    const int Np = N_ * D;

    const float* mu_a = ws;
    const float* va   = ws + (size_t)Np;
    const float* mu_b = ws + (size_t)2 * Np;
    const float* vb   = ws + (size_t)3 * Np;
    float* partials   = ws + (size_t)4 * Np;

    // ---- decode block -> (set, i-tile, j-tile, chunk) ----
    const int c = blockIdx.x & (DCHUNKS - 1);
    const int t = blockIdx.x >> 4;           // DCHUNKS == 16
    int set, it, jt;
    if (t >= 2 * TRI_TILES) {
        set = 2;
        const int tt = t - 2 * TRI_TILES;
        it = tt >> 3;
        jt = tt & 7;
    } else {
        set = (t >= TRI_TILES) ? 1 : 0;
        const int tt = set ? (t - TRI_TILES) : t;
        int g = 0, cum = 0;
        while (cum + (g >> 1) + 1 <= tt) { cum += (g >> 1) + 1; ++g; }
        it = g;
        jt = tt - cum;
    }
    const int i0 = it * 4, j0 = jt * 8;

    const float *mu1, *v1, *mu2, *v2;
    if (set == 0)      { mu1 = mu2 = mu_a; v1 = v2 = va; }
    else if (set == 1) { mu1 = mu2 = mu_b; v1 = v2 = vb; }
    else               { mu1 = mu_a; v1 = va; mu2 = mu_b; v2 = vb; }

#define TERM(acc, mx1, sx1, mx2, sx2)                                  \
    {                                                                  \
        float v  = (sx1) + (sx2);                                      \
        float rs = __builtin_amdgcn_rsqf(v);                           \
        float d  = (mx1) - (mx2);                                      \
        float t_ = d * rs;                                             \
        float e  = __builtin_amdgcn_exp2f(-(t_ * t_));                 \
        acc = fmaf(e, rs, acc);                                        \
    }

    float accs[4][8];
    #pragma unroll
    for (int ir = 0; ir < 4; ++ir)
        #pragma unroll
        for (int j8 = 0; j8 < 8; ++j8) accs[ir][j8] = 0.0f;

    if (D == 16384) {
        // Fast path: chunk = 1024 elems = 256 threads x 1 float4.
        const int base = (c << 10) + ((int)threadIdx.x << 2);
        float4 im[4], iv[4];
        #pragma unroll
        for (int ir = 0; ir < 4; ++ir) {
            im[ir] = *(const float4*)(mu1 + (size_t)(i0 + ir) * 16384 + base);
            iv[ir] = *(const float4*)(v1  + (size_t)(i0 + ir) * 16384 + base);
        }
        #pragma unroll
        for (int j8 = 0; j8 < 8; ++j8) {
            const float4 jm = *(const float4*)(mu2 + (size_t)(j0 + j8) * 16384 + base);
            const float4 jv = *(const float4*)(v2  + (size_t)(j0 + j8) * 16384 + base);
            #pragma unroll
            for (int ir = 0; ir < 4; ++ir) {
                TERM(accs[ir][j8], im[ir].x, iv[ir].x, jm.x, jv.x)
                TERM(accs[ir][j8], im[ir].y, iv[ir].y, jm.y, jv.y)
                TERM(accs[ir][j8], im[ir].z, iv[ir].z, jm.z, jv.z)
                TERM(accs[ir][j8], im[ir].w, iv[ir].w, jm.w, jv.w)
            }
        }
    } else {
        // Generic fallback: chunk c covers [c*D/16, (c+1)*D/16), scalar loads.
        const int cs = D / DCHUNKS;
        const int lo = c * cs, hi = lo + cs;
        for (int e = lo + (int)threadIdx.x; e < hi; e += 256) {
            #pragma unroll
            for (int j8 = 0; j8 < 8; ++j8) {
                const float mj = mu2[(size_t)(j0 + j8) * D + e];
                const float vj = v2 [(size_t)(j0 + j8) * D + e];
                #pragma unroll
                for (int ir = 0; ir < 4; ++ir) {
                    const float mi = mu1[(size_t)(i0 + ir) * D + e];
                    const float vi = v1 [(size_t)(i0 + ir) * D + e];
                    TERM(accs[ir][j8], mi, vi, mj, vj)
                }
            }
        }
    }
#undef TERM

    float tot = 0.0f;
    #pragma unroll
    for (int ir = 0; ir < 4; ++ir) {
        #pragma unroll
        for (int j8 = 0; j8 < 8; ++j8) {
            float w;
            if (set == 2) w = -2.0f;
            else {
                const int ii = i0 + ir, jj = j0 + j8;
                w = (jj > ii) ? 0.0f : (jj == ii) ? 1.0f : 2.0f;
            }
            tot = fmaf(w, accs[ir][j8], tot);
        }
    }
    tot *= SQRT_2LN2;   // fold the var'-prescale correction once

    for (int off = 32; off > 0; off >>= 1)
        tot += __shfl_down(tot, off, 64);
    __shared__ float wsum[4];
    const int lane = threadIdx.x & 63;
    const int wid  = threadIdx.x >> 6;
    if (lane == 0) wsum[wid] = tot;
    __syncthreads();
    if (threadIdx.x == 0) {
        partials[blockIdx.x] = wsum[0] + wsum[1] + wsum[2] + wsum[3];
    }
}

// Single block: sum the PAIR_BLOCKS partials into out[0].
__global__ __launch_bounds__(256) void reduce_kernel(const float* __restrict__ ws,
                                                     const int* __restrict__ kern_p,
                                                     float* __restrict__ out) {
    const int k = kern_p[0];
    const int D  = C_ * (H_ / k) * (W_ / k);
    const int Np = N_ * D;
    const float* partials = ws + (size_t)4 * Np;

    float s = 0.0f;
    for (int p = threadIdx.x; p < PAIR_BLOCKS; p += 256) s += partials[p];
    for (int off = 32; off > 0; off >>= 1)
        s += __shfl_down(s, off, 64);
    __shared__ float wsum[4];
    const int lane = threadIdx.x & 63;
    const int wid  = threadIdx.x >> 6;
    if (lane == 0) wsum[wid] = s;
    __syncthreads();
    if (threadIdx.x == 0) out[0] = wsum[0] + wsum[1] + wsum[2] + wsum[3];
}

extern "C" void kernel_launch(void* const* d_in, const int* in_sizes, int n_in,
                              void* d_out, int out_size, void* d_ws, size_t ws_size,
                              hipStream_t stream) {
    const float* mu_a = (const float*)d_in[0];
    const float* lv_a = (const float*)d_in[1];
    const float* mu_b = (const float*)d_in[2];
    const float* lv_b = (const float*)d_in[3];
    const int*   kern = (const int*)d_in[4];
    float* out = (float*)d_out;
    float* ws  = (float*)d_ws;

    pool_kernel<<<4096, 256, 0, stream>>>(mu_a, lv_a, mu_b, lv_b, kern, ws);
    pair_kernel<<<PAIR_BLOCKS, 256, 0, stream>>>(ws, kern);
    reduce_kernel<<<1, 256, 0, stream>>>(ws, kern, out);
}